// Round 11
// baseline (2699.766 us; speedup 1.0000x reference)
//
#include <hip/hip_runtime.h>
#include <math.h>

#define NN 4096
#define BB 4
#define NPT (NN*BB)
#define KK 20
#define EPSB 1e-5f

#define AS_STRIDE 132   // 128-point c-row, padded
#define WS_STRIDE 68    // 64-col c-row, padded
// Non-wrapping per-channel skew: staging writes 2-way (free), reads clean,
// all offsets multiples of 4 floats so float4 reads stay 16B-aligned.
#define SKEW(c) ((((((c)>>2)&7))<<2) + (((c)>>5)*28))

__device__ __forceinline__ float lrelu(float x){ return x >= 0.f ? x : 0.2f*x; }

// (val desc, idx asc) total order — matches jax.lax.top_k tie-breaking
__device__ __forceinline__ bool kbetter(float v1, int i1, float v2, int i2){
  return (v1 > v2) || (v1 == v2 && i1 < i2);
}

// ---- stage 1: conv1 (3->64), writes raw into xcat[:, 0:64] (point-major, row stride 192)
__global__ void conv1_kernel(const float* __restrict__ x, const float* __restrict__ W1,
                             float* __restrict__ xcat){
  __shared__ float Wl[192];
  int tid = threadIdx.x;
  if (tid < 192) Wl[tid] = W1[tid];
  __syncthreads();
  int p = blockIdx.x*4 + (tid >> 6);
  int o = tid & 63;
  int b = p >> 12, n = p & 4095;
  const float* xb = x + (size_t)b*3*NN + n;
  float acc = Wl[o*3+0]*xb[0] + Wl[o*3+1]*xb[NN] + Wl[o*3+2]*xb[2*NN];
  xcat[(size_t)p*192 + o] = acc;
}

// ---- per-channel partial stats for point-major (NPT, C) buffer; deterministic slots
__global__ void stats_pm_kernel(const float* __restrict__ buf, int stride, int ofs,
                                float* __restrict__ psum, float* __restrict__ psumsq, int C){
  int tid = threadIdx.x;
  int lane = tid & 63, g = tid >> 6;
  int o = blockIdx.x*64 + lane;
  int p0 = blockIdx.y*256 + g*64;
  float s = 0.f, ss = 0.f;
  for (int i = 0; i < 64; ++i){
    float v = buf[(size_t)(p0+i)*stride + ofs + o];
    s += v; ss += v*v;
  }
  __shared__ float rs[4][64], rss[4][64];
  rs[g][lane] = s; rss[g][lane] = ss;
  __syncthreads();
  if (g == 0){
    s  = rs[0][lane]+rs[1][lane]+rs[2][lane]+rs[3][lane];
    ss = rss[0][lane]+rss[1][lane]+rss[2][lane]+rss[3][lane];
    psum[(size_t)blockIdx.y*C + o] = s;
    psumsq[(size_t)blockIdx.y*C + o] = ss;
  }
}

// deterministic finalize: serial sum over nparts partials per channel
__global__ void bn_finalize_kernel(const float* __restrict__ psum, const float* __restrict__ psumsq,
                                   int nparts,
                                   const float* __restrict__ gamma, const float* __restrict__ beta,
                                   float* __restrict__ scale, float* __restrict__ shift,
                                   float invcnt, int C){
  int o = threadIdx.x + blockIdx.x*blockDim.x;
  if (o >= C) return;
  float s = 0.f, ss = 0.f;
  for (int i = 0; i < nparts; ++i){
    s  += psum[(size_t)i*C + o];
    ss += psumsq[(size_t)i*C + o];
  }
  float m = s*invcnt;
  float v = ss*invcnt - m*m;
  v = fmaxf(v, 0.f);
  float sc = gamma[o] * rsqrtf(v + EPSB);
  scale[o] = sc;
  shift[o] = beta[o] - m*sc;
}

__global__ void apply_bn_kernel(float* __restrict__ buf, int stride, int ofs, int log2C,
                                const float* __restrict__ scale, const float* __restrict__ shift){
  int i = blockIdx.x*256 + threadIdx.x;
  int o = i & ((1<<log2C)-1);
  int p = i >> log2C;
  size_t a = (size_t)p*stride + ofs + o;
  float e = buf[a]*scale[o] + shift[o];
  buf[a] = lrelu(e);
}

// ---- ||x||^2 per point (64 features)
__global__ void xx_kernel(const float* __restrict__ xcat, int stride, int ofs,
                          float* __restrict__ xx){
  int p = blockIdx.x*256 + threadIdx.x;
  const float4* r = (const float4*)(xcat + (size_t)p*stride + ofs);
  float s = 0.f;
  #pragma unroll
  for (int i = 0; i < 16; ++i){ float4 v = r[i]; s += v.x*v.x + v.y*v.y + v.z*v.z + v.w*v.w; }
  xx[p] = s;
}

// ---- FUSED KNN: never materializes dist. Grid (32 row-tiles, 4 m-splits, BB).
// Block: stage 128 rows' features once; loop 16 chunks of 64 m-cols:
//   compute dist tile (bit-identical FMA chain to the old dist_kernel),
//   dump 64-row halves to Sel LDS, all 256 threads stream-scan (2 threads/row,
//   32 cols each) into register top-20 under (val desc, idx asc).
// Epilogue: each thread writes its 20-entry list; knnmerge merges 8 lists/row.
__global__ void __launch_bounds__(256, 2)
knn_kernel(const float* __restrict__ xcat, int ofs, const float* __restrict__ xx,
           float* __restrict__ candV, int* __restrict__ candI){
  __shared__ float As[64*AS_STRIDE + 64];
  __shared__ float Bs[64*WS_STRIDE + 64];
  __shared__ float Sel[64*65];
  int tid = threadIdx.x;
  int rt = blockIdx.x, ms = blockIdx.y, b = blockIdx.z;
  int n0 = rt*128;
  const float* base = xcat + (size_t)b*NN*192 + ofs;
  // stage As: 128 rows x 64 ch, c-major skewed (same pattern as old dist)
  #pragma unroll
  for (int j = 0; j < 8; ++j){
    int slot = tid + 256*j;
    int row = slot >> 4, c4 = (slot & 15)*4;
    float4 v = *(const float4*)(base + (size_t)(n0+row)*192 + c4);
    As[(c4+0)*AS_STRIDE+SKEW(c4+0)+row]=v.x; As[(c4+1)*AS_STRIDE+SKEW(c4+1)+row]=v.y;
    As[(c4+2)*AS_STRIDE+SKEW(c4+2)+row]=v.z; As[(c4+3)*AS_STRIDE+SKEW(c4+3)+row]=v.w;
  }
  int pA = (tid >> 4)*4, oB = (tid & 15)*4;
  float xn[8];
  #pragma unroll
  for (int i = 0; i < 4; ++i){
    xn[i]   = xx[b*NN + n0 + pA + i];
    xn[4+i] = xx[b*NN + n0 + 64 + pA + i];
  }
  // selection ownership: 2 threads per row (col halves of 32 within each chunk)
  int srow  = (tid < 128) ? (tid >> 1) : 64 + ((tid - 128) >> 1);
  int shalf = tid & 1;
  float tv[20]; int ti[20];
  #pragma unroll
  for (int s = 0; s < 20; ++s){ tv[s] = -INFINITY; ti[s] = 0x7fffffff; }
  for (int ch = 0; ch < 16; ++ch){
    int m0 = ms*1024 + ch*64;
    // stage Bs: 64 cols x 64 ch
    #pragma unroll
    for (int j = 0; j < 4; ++j){
      int slot = tid + 256*j;
      int col = slot >> 4, c4 = (slot & 15)*4;
      float4 v = *(const float4*)(base + (size_t)(m0+col)*192 + c4);
      Bs[(c4+0)*WS_STRIDE+SKEW(c4+0)+col]=v.x; Bs[(c4+1)*WS_STRIDE+SKEW(c4+1)+col]=v.y;
      Bs[(c4+2)*WS_STRIDE+SKEW(c4+2)+col]=v.z; Bs[(c4+3)*WS_STRIDE+SKEW(c4+3)+col]=v.w;
    }
    __syncthreads();   // Bs ready; also: prev chunk's Sel scans complete
    float acc[8][4] = {};
    for (int c = 0; c < 64; ++c){
      const float* arow = &As[c*AS_STRIDE + SKEW(c)];
      const float* brow = &Bs[c*WS_STRIDE + SKEW(c)];
      float4 a0 = *(const float4*)&arow[pA];
      float4 a1 = *(const float4*)&arow[pA + 64];
      float4 bb = *(const float4*)&brow[oB];
      float av[8] = {a0.x,a0.y,a0.z,a0.w,a1.x,a1.y,a1.z,a1.w};
      float bv[4] = {bb.x,bb.y,bb.z,bb.w};
      #pragma unroll
      for (int i = 0; i < 8; ++i)
        #pragma unroll
        for (int j = 0; j < 4; ++j)
          acc[i][j] += av[i]*bv[j];
    }
    float xm[4];
    #pragma unroll
    for (int j = 0; j < 4; ++j) xm[j] = xx[b*NN + m0 + oB + j];
    #pragma unroll
    for (int h = 0; h < 2; ++h){
      // dump this half's dist values to Sel (rows h*64+pA..+3)
      #pragma unroll
      for (int i = 0; i < 4; ++i){
        int ai = h*4 + i;
        float4 w;
        w.x = 2.f*acc[ai][0] - xn[ai] - xm[0];
        w.y = 2.f*acc[ai][1] - xn[ai] - xm[1];
        w.z = 2.f*acc[ai][2] - xn[ai] - xm[2];
        w.w = 2.f*acc[ai][3] - xn[ai] - xm[3];
        *(float4*)&Sel[(pA+i)*65 + oB] = w;
      }
      __syncthreads();  // Sel ready
      if ((h == 0) == (tid < 128)){
        int lrow = srow - h*64;
        const float* sp = &Sel[lrow*65 + shalf*32];
        int mbase = m0 + shalf*32;
        for (int i2 = 0; i2 < 32; ++i2){
          float v = sp[i2]; int id = mbase + i2;
          if (kbetter(v, id, tv[19], ti[19])){
            float cv = v; int ci = id;
            #pragma unroll
            for (int s = 0; s < 20; ++s){
              bool takes = kbetter(cv, ci, tv[s], ti[s]);
              float nv = takes ? cv : tv[s]; int ni = takes ? ci : ti[s];
              cv = takes ? tv[s] : cv;       ci = takes ? ti[s] : ci;
              tv[s] = nv; ti[s] = ni;
            }
          }
        }
      }
      __syncthreads();  // scans done before Sel overwrite
    }
  }
  size_t o = ((size_t)((b*4 + ms)*2 + shalf)*NN + n0 + srow)*KK;
  #pragma unroll
  for (int s = 0; s < 20; ++s){ candV[o+s] = tv[s]; candI[o+s] = ti[s]; }
}

// ---- merge 8 per-row candidate lists -> final idx (set semantics; exact tie order)
__global__ void knnmerge_kernel(const float* __restrict__ candV, const int* __restrict__ candI,
                                int* __restrict__ idxout){
  int r = blockIdx.x*256 + threadIdx.x;   // b*4096 + n
  int b = r >> 12, n = r & 4095;
  float tv[20]; int ti[20];
  #pragma unroll
  for (int s = 0; s < 20; ++s){ tv[s] = -INFINITY; ti[s] = 0x7fffffff; }
  for (int q = 0; q < 8; ++q){
    size_t o = ((size_t)(b*8 + q)*NN + n)*KK;
    for (int k = 0; k < KK; ++k){
      float v = candV[o+k]; int id = candI[o+k];
      if (kbetter(v, id, tv[19], ti[19])){
        float cv = v; int ci = id;
        #pragma unroll
        for (int s = 0; s < 20; ++s){
          bool takes = kbetter(cv, ci, tv[s], ti[s]);
          float nv = takes ? cv : tv[s]; int ni = takes ? ci : ti[s];
          cv = takes ? tv[s] : cv;       ci = takes ? ti[s] : ci;
          tv[s] = nv; ti[s] = ni;
        }
      }
    }
  }
  int* orow = idxout + (size_t)r*KK;
  #pragma unroll
  for (int s = 0; s < 20; ++s) orow[s] = ti[s];
}

// ---- U = W[:, :64] * x ; T = (W[:,64:] - W[:, :64]) * x  (per point, point-major out)
__global__ void ut_kernel(const float* __restrict__ xcat, int ofs, const float* __restrict__ W,
                          float* __restrict__ U, float* __restrict__ T){
  __shared__ float Wl[64*129];
  int tid = threadIdx.x;
  for (int i = tid; i < 64*128; i += 256){
    int o = i >> 7, c = i & 127;
    Wl[o*129 + c] = W[i];
  }
  __syncthreads();
  int g = tid >> 6, lane = tid & 63;
  int p = blockIdx.x*4 + g;
  float xv = xcat[(size_t)p*192 + ofs + lane];
  const float* wr = Wl + lane*129;
  float u = 0.f, t = 0.f;
  for (int c = 0; c < 64; ++c){
    float xc = __shfl(xv, c);
    float wa = wr[c], wb = wr[64+c];
    u += wa*xc;
    t += (wb - wa)*xc;
  }
  U[(size_t)p*64 + lane] = u;
  T[(size_t)p*64 + lane] = t;
}

// ---- ONE gather pass: v = U[j]+T[n] over k -> per-channel partial sum/sumsq
// (deterministic slots) AND per-(point,ch) vmax/vmin (for the lrelu-monotone max trick).
__global__ void gather_kernel(const float* __restrict__ U, const float* __restrict__ T,
                              const int* __restrict__ idx,
                              float* __restrict__ psum, float* __restrict__ psumsq,
                              float* __restrict__ vmax, float* __restrict__ vmin){
  int tid = threadIdx.x;
  int g = tid >> 6, lane = tid & 63;
  int p0 = blockIdx.x*64 + g*16;
  float s = 0.f, ss = 0.f;
  for (int pi = 0; pi < 16; ++pi){
    int p = p0 + pi;
    int base = (p >> 12) << 12;
    float t = T[(size_t)p*64 + lane];
    const int* ir = idx + (size_t)p*KK;
    float mx = -INFINITY, mn = INFINITY;
    for (int k = 0; k < KK; ++k){
      int j = ir[k];
      float v = U[(size_t)(base + j)*64 + lane] + t;
      s += v; ss += v*v;
      mx = fmaxf(mx, v); mn = fminf(mn, v);
    }
    vmax[(size_t)p*64 + lane] = mx;
    vmin[(size_t)p*64 + lane] = mn;
  }
  __shared__ float rs[4][64], rss[4][64];
  rs[g][lane] = s; rss[g][lane] = ss;
  __syncthreads();
  if (g == 0){
    s  = rs[0][lane]+rs[1][lane]+rs[2][lane]+rs[3][lane];
    ss = rss[0][lane]+rss[1][lane]+rss[2][lane]+rss[3][lane];
    psum[(size_t)blockIdx.x*64 + lane] = s;
    psumsq[(size_t)blockIdx.x*64 + lane] = ss;
  }
}

// ---- elementwise: x_out[p,o] = lrelu(s*(s>=0?vmax:vmin)+t) -> xcat[:, ofs:ofs+64]
__global__ void gapply_kernel(const float* __restrict__ vmax, const float* __restrict__ vmin,
                              const float* __restrict__ scale, const float* __restrict__ shift,
                              float* __restrict__ xcat, int ofs){
  int i = blockIdx.x*256 + threadIdx.x;
  int p = i >> 6, o = i & 63;
  float s = scale[o];
  float v = (s >= 0.f) ? vmax[i] : vmin[i];
  xcat[(size_t)p*192 + ofs + o] = lrelu(s*v + shift[o]);
}

// ---- point-major matmul, 128p x 64o tile, 8x4 acc/thread (used for conv7).
// Staging split into load-all-registers then write-LDS phases (MLP on global loads).
__global__ void __launch_bounds__(256, 2)
mm_kernel(const float* __restrict__ in, int inStride, int inOfs,
          const float* __restrict__ W, int wStride,
          float* __restrict__ out, int outStride,
          const float* __restrict__ bias, int O, int I,
          const float* __restrict__ bnScale, const float* __restrict__ bnShift){
  __shared__ float As[64*AS_STRIDE + 64];
  __shared__ float Ws[64*WS_STRIDE + 64];
  int tid = threadIdx.x;
  int p0 = blockIdx.x*128, o0 = blockIdx.y*64;
  int psub = (tid >> 4)*8, osub = (tid & 15)*4;
  int cgrp = (tid & 15)*4;
  float acc[8][4] = {};
  for (int cc = 0; cc < I; cc += 64){
    float4 sc4 = make_float4(1.f,1.f,1.f,1.f), sh4 = make_float4(0.f,0.f,0.f,0.f);
    if (bnScale){
      sc4 = *(const float4*)(bnScale + cc + cgrp);
      sh4 = *(const float4*)(bnShift + cc + cgrp);
    }
    float4 vin[8], vw[4];
    #pragma unroll
    for (int j = 0; j < 8; ++j){
      int row = (tid + 256*j) >> 4;
      vin[j] = *(const float4*)(in + (size_t)(p0+row)*inStride + inOfs + cc + cgrp);
    }
    #pragma unroll
    for (int j = 0; j < 4; ++j){
      int row = (tid + 256*j) >> 4;
      vw[j] = *(const float4*)(W + (size_t)(o0+row)*wStride + cc + cgrp);
    }
    #pragma unroll
    for (int j = 0; j < 8; ++j){
      int row = (tid + 256*j) >> 4, c4 = cgrp;
      float4 v = vin[j];
      if (bnScale){
        v.x = lrelu(v.x*sc4.x + sh4.x); v.y = lrelu(v.y*sc4.y + sh4.y);
        v.z = lrelu(v.z*sc4.z + sh4.z); v.w = lrelu(v.w*sc4.w + sh4.w);
      }
      As[(c4+0)*AS_STRIDE+SKEW(c4+0)+row]=v.x; As[(c4+1)*AS_STRIDE+SKEW(c4+1)+row]=v.y;
      As[(c4+2)*AS_STRIDE+SKEW(c4+2)+row]=v.z; As[(c4+3)*AS_STRIDE+SKEW(c4+3)+row]=v.w;
    }
    #pragma unroll
    for (int j = 0; j < 4; ++j){
      int row = (tid + 256*j) >> 4, c4 = cgrp;
      float4 v = vw[j];
      Ws[(c4+0)*WS_STRIDE+SKEW(c4+0)+row]=v.x; Ws[(c4+1)*WS_STRIDE+SKEW(c4+1)+row]=v.y;
      Ws[(c4+2)*WS_STRIDE+SKEW(c4+2)+row]=v.z; Ws[(c4+3)*WS_STRIDE+SKEW(c4+3)+row]=v.w;
    }
    __syncthreads();
    for (int c = 0; c < 64; ++c){
      const float* arow = &As[c*AS_STRIDE + SKEW(c)];
      const float* brow = &Ws[c*WS_STRIDE + SKEW(c)];
      float4 a0 = *(const float4*)&arow[psub];
      float4 a1 = *(const float4*)&arow[psub + 4];
      float4 bb = *(const float4*)&brow[osub];
      float av[8] = {a0.x,a0.y,a0.z,a0.w,a1.x,a1.y,a1.z,a1.w};
      float bv[4] = {bb.x,bb.y,bb.z,bb.w};
      #pragma unroll
      for (int i = 0; i < 8; ++i)
        #pragma unroll
        for (int j = 0; j < 4; ++j)
          acc[i][j] += av[i]*bv[j];
    }
    __syncthreads();
  }
  int bIdx = p0 >> 12;
  float bb0=0.f, bb1=0.f, bb2=0.f, bb3=0.f;
  if (bias){
    bb0 = bias[bIdx*O + o0 + osub + 0];
    bb1 = bias[bIdx*O + o0 + osub + 1];
    bb2 = bias[bIdx*O + o0 + osub + 2];
    bb3 = bias[bIdx*O + o0 + osub + 3];
  }
  #pragma unroll
  for (int i = 0; i < 8; ++i){
    float4 w;
    w.x = acc[i][0]+bb0; w.y = acc[i][1]+bb1; w.z = acc[i][2]+bb2; w.w = acc[i][3]+bb3;
    *(float4*)(out + (size_t)(p0+psub+i)*outStride + o0 + osub) = w;
  }
}

// ---- point-major matmul, 128p x 128o tile, 8x8 acc/thread, SPLIT fragments
// (conflict-free reads). Staging split into load-then-write phases. conv4/5/6.
__global__ void __launch_bounds__(256, 2)
mm128_kernel(const float* __restrict__ in, int inStride, int inOfs,
             const float* __restrict__ W, int wStride,
             float* __restrict__ out, int outStride,
             const float* __restrict__ bias, int O, int I,
             const float* __restrict__ bnScale, const float* __restrict__ bnShift){
  __shared__ float As[64*AS_STRIDE + 64];
  __shared__ float Ws[64*AS_STRIDE + 64];
  int tid = threadIdx.x;
  int p0 = blockIdx.x*128, o0 = blockIdx.y*128;
  int pA = (tid >> 4)*4, oB = (tid & 15)*4;
  int cgrp = (tid & 15)*4;
  float acc[8][8] = {};
  for (int cc = 0; cc < I; cc += 64){
    float4 sc4 = make_float4(1.f,1.f,1.f,1.f), sh4 = make_float4(0.f,0.f,0.f,0.f);
    if (bnScale){
      sc4 = *(const float4*)(bnScale + cc + cgrp);
      sh4 = *(const float4*)(bnShift + cc + cgrp);
    }
    float4 vin[8], vw[8];
    #pragma unroll
    for (int j = 0; j < 8; ++j){
      int row = (tid + 256*j) >> 4;
      vin[j] = *(const float4*)(in + (size_t)(p0+row)*inStride + inOfs + cc + cgrp);
      vw[j]  = *(const float4*)(W + (size_t)(o0+row)*wStride + cc + cgrp);
    }
    #pragma unroll
    for (int j = 0; j < 8; ++j){
      int row = (tid + 256*j) >> 4, c4 = cgrp;
      float4 v = vin[j];
      if (bnScale){
        v.x = lrelu(v.x*sc4.x + sh4.x); v.y = lrelu(v.y*sc4.y + sh4.y);
        v.z = lrelu(v.z*sc4.z + sh4.z); v.w = lrelu(v.w*sc4.w + sh4.w);
      }
      As[(c4+0)*AS_STRIDE+SKEW(c4+0)+row]=v.x; As[(c4+1)*AS_STRIDE+SKEW(c4+1)+row]=v.y;
      As[(c4+2)*AS_STRIDE+SKEW(c4+2)+row]=v.z; As[(c4+3)*AS_STRIDE+SKEW(c4+3)+row]=v.w;
      float4 w = vw[j];
      Ws[(c4+0)*AS_STRIDE+SKEW(c4+0)+row]=w.x; Ws[(c4+1)*AS_STRIDE+SKEW(c4+1)+row]=w.y;
      Ws[(c4+2)*AS_STRIDE+SKEW(c4+2)+row]=w.z; Ws[(c4+3)*AS_STRIDE+SKEW(c4+3)+row]=w.w;
    }
    __syncthreads();
    for (int c = 0; c < 64; ++c){
      const float* arow = &As[c*AS_STRIDE + SKEW(c)];
      const float* brow = &Ws[c*AS_STRIDE + SKEW(c)];
      float4 a0 = *(const float4*)&arow[pA];
      float4 a1 = *(const float4*)&arow[pA + 64];
      float4 b0 = *(const float4*)&brow[oB];
      float4 b1 = *(const float4*)&brow[oB + 64];
      float av[8] = {a0.x,a0.y,a0.z,a0.w,a1.x,a1.y,a1.z,a1.w};
      float bv[8] = {b0.x,b0.y,b0.z,b0.w,b1.x,b1.y,b1.z,b1.w};
      #pragma unroll
      for (int i = 0; i < 8; ++i)
        #pragma unroll
        for (int j = 0; j < 8; ++j)
          acc[i][j] += av[i]*bv[j];
    }
    __syncthreads();
  }
  int bIdx = p0 >> 12;
  float bb[8] = {0.f,0.f,0.f,0.f,0.f,0.f,0.f,0.f};
  if (bias){
    #pragma unroll
    for (int j = 0; j < 4; ++j){
      bb[j]   = bias[bIdx*O + o0 + oB + j];
      bb[4+j] = bias[bIdx*O + o0 + 64 + oB + j];
    }
  }
  #pragma unroll
  for (int h = 0; h < 2; ++h){
    #pragma unroll
    for (int i = 0; i < 4; ++i){
      int row = p0 + h*64 + pA + i;
      int ai = h*4 + i;
      float4 w0, w1;
      w0.x = acc[ai][0]+bb[0]; w0.y = acc[ai][1]+bb[1];
      w0.z = acc[ai][2]+bb[2]; w0.w = acc[ai][3]+bb[3];
      w1.x = acc[ai][4]+bb[4]; w1.y = acc[ai][5]+bb[5];
      w1.z = acc[ai][6]+bb[6]; w1.w = acc[ai][7]+bb[7];
      float* orow = out + (size_t)row*outStride + o0;
      *(float4*)(orow + oB) = w0;
      *(float4*)(orow + 64 + oB) = w1;
    }
  }
}

// ---- stats + per-(b,tile) min/max over r4 (point-major, stride 512); deterministic slots
__global__ void stats4_kernel(const float* __restrict__ r4,
                              float* __restrict__ psum, float* __restrict__ psumsq,
                              float* __restrict__ pmax, float* __restrict__ pmin){
  int tid = threadIdx.x;
  int lane = tid & 63, g = tid >> 6;
  int o = blockIdx.x*64 + lane;
  int p0 = blockIdx.y*256 + g*64;
  float s = 0.f, ss = 0.f, mx = -INFINITY, mn = INFINITY;
  for (int i = 0; i < 64; ++i){
    float v = r4[(size_t)(p0+i)*512 + o];
    s += v; ss += v*v; mx = fmaxf(mx, v); mn = fminf(mn, v);
  }
  __shared__ float rs[4][64], rss[4][64], rmx[4][64], rmn[4][64];
  rs[g][lane]=s; rss[g][lane]=ss; rmx[g][lane]=mx; rmn[g][lane]=mn;
  __syncthreads();
  if (g == 0){
    psum [(size_t)blockIdx.y*512 + o] = rs[0][lane]+rs[1][lane]+rs[2][lane]+rs[3][lane];
    psumsq[(size_t)blockIdx.y*512 + o] = rss[0][lane]+rss[1][lane]+rss[2][lane]+rss[3][lane];
    pmax [(size_t)blockIdx.y*512 + o] = fmaxf(fmaxf(rmx[0][lane],rmx[1][lane]), fmaxf(rmx[2][lane],rmx[3][lane]));
    pmin [(size_t)blockIdx.y*512 + o] = fminf(fminf(rmn[0][lane],rmn[1][lane]), fminf(rmn[2][lane],rmn[3][lane]));
  }
}

// lrelu(s*v+t) monotone in v: use max if s>=0 else min  (16 tiles per batch)
__global__ void x6v_kernel(const float* __restrict__ pmax, const float* __restrict__ pmin,
                           const float* __restrict__ scale, const float* __restrict__ shift,
                           float* __restrict__ x6v){
  int t = blockIdx.x*256 + threadIdx.x;
  int b = t >> 9, o = t & 511;
  float mx = -INFINITY, mn = INFINITY;
  for (int pt = b*16; pt < b*16+16; ++pt){
    mx = fmaxf(mx, pmax[(size_t)pt*512 + o]);
    mn = fminf(mn, pmin[(size_t)pt*512 + o]);
  }
  float s = scale[o];
  float v = (s >= 0.f) ? mx : mn;
  x6v[t] = lrelu(s*v + shift[o]);
}

// bias5[b,o] = sum_c W5[o, 192+c] * x6v[b,c]   (the broadcast part of the concat)
__global__ void bias5_kernel(const float* __restrict__ W5, const float* __restrict__ x6v,
                             float* __restrict__ b5){
  __shared__ float xl[512];
  int tid = threadIdx.x;
  int t = blockIdx.x*256 + tid;
  int b = t >> 9, o = t & 511;
  for (int i = tid; i < 512; i += 256) xl[i] = x6v[(b<<9) + i];
  __syncthreads();
  const float* wr = W5 + (size_t)o*704 + 192;
  float acc = 0.f;
  for (int c = 0; c < 512; ++c) acc += wr[c]*xl[c];
  b5[t] = acc;
}

// ---- conv8 (128->2) + bias over raw r7 with BN7+lrelu applied inline
__global__ void conv8_kernel(const float* __restrict__ r7, const float* __restrict__ W8,
                             const float* __restrict__ bias8,
                             const float* __restrict__ scale, const float* __restrict__ shift,
                             float* __restrict__ out){
  __shared__ float Wl[256];
  __shared__ float scl[128], shl[128];
  int tid = threadIdx.x;
  Wl[tid] = W8[tid];
  if (tid < 128){ scl[tid] = scale[tid]; shl[tid] = shift[tid]; }
  __syncthreads();
  int p = blockIdx.x*256 + tid;
  int b = p >> 12, n = p & 4095;
  const float4* row = (const float4*)(r7 + (size_t)p*128);
  float a0 = 0.f, a1 = 0.f;
  #pragma unroll
  for (int i = 0; i < 32; ++i){
    float4 v = row[i];
    v.x = lrelu(v.x*scl[i*4+0] + shl[i*4+0]);
    v.y = lrelu(v.y*scl[i*4+1] + shl[i*4+1]);
    v.z = lrelu(v.z*scl[i*4+2] + shl[i*4+2]);
    v.w = lrelu(v.w*scl[i*4+3] + shl[i*4+3]);
    a0 += v.x*Wl[i*4] + v.y*Wl[i*4+1] + v.z*Wl[i*4+2] + v.w*Wl[i*4+3];
    a1 += v.x*Wl[128+i*4] + v.y*Wl[128+i*4+1] + v.z*Wl[128+i*4+2] + v.w*Wl[128+i*4+3];
  }
  out[(size_t)(b*2+0)*NN + n] = a0 + bias8[0];
  out[(size_t)(b*2+1)*NN + n] = a1 + bias8[1];
}

extern "C" void kernel_launch(void* const* d_in, const int* in_sizes, int n_in,
                              void* d_out, int out_size, void* d_ws, size_t ws_size,
                              hipStream_t stream){
  const float* x     = (const float*)d_in[0];
  const float* W1    = (const float*)d_in[1];
  const float* W2    = (const float*)d_in[2];
  const float* W3    = (const float*)d_in[3];
  const float* W4    = (const float*)d_in[4];
  const float* W5    = (const float*)d_in[5];
  const float* W6    = (const float*)d_in[6];
  const float* W7    = (const float*)d_in[7];
  const float* W8    = (const float*)d_in[8];
  const float* bias8 = (const float*)d_in[9];
  const float* gamma[8]; const float* beta[8];
  for (int i = 1; i <= 7; ++i){
    gamma[i] = (const float*)d_in[10 + 2*(i-1)];
    beta[i]  = (const float*)d_in[11 + 2*(i-1)];
  }
  float* out = (float*)d_out;

  float* ws = (float*)d_ws;
  size_t off = 0;
  float* xcat  = ws + off; off += (size_t)NPT*192;   // x1|x2|x3 packed, stride 192
  float* U     = ws + off; off += (size_t)NPT*64;
  float* T     = ws + off; off += (size_t)NPT*64;
  float* xx    = ws + off; off += NPT;
  int*   idx   = (int*)(ws + off); off += (size_t)NPT*KK;
  float* psum  = ws + off; off += 64*512;
  float* psumsq= ws + off; off += 64*512;
  float* pmax  = ws + off; off += 64*512;
  float* pmin  = ws + off; off += 64*512;
  float* scale = ws + off; off += 512;
  float* shift = ws + off; off += 512;
  float* x6v   = ws + off; off += 2048;
  float* b5    = ws + off; off += 2048;
  float* big   = ws + off;   // time-shared: cand (knn) / vmax|vmin (gather) / r4 / r5|r6|r7
  float* candV = big;                               // 32 lists x 4096 x 20
  int*   candI = (int*)(big + (size_t)32*NN*KK);
  float* vmaxB = big;                               // NPT*64, live only between knn rounds
  float* vminB = big + (size_t)NPT*64;
  float* r4    = big;
  float* r5    = big;
  float* r6    = big + (size_t)NPT*512;
  float* r7    = big + (size_t)NPT*512 + (size_t)NPT*256;

  // ---- stage 1: conv1 + BN(train stats) + lrelu -> x1 (xcat[:,0:64])
  conv1_kernel<<<NPT/4, 256, 0, stream>>>(x, W1, xcat);
  stats_pm_kernel<<<dim3(1,64), 256, 0, stream>>>(xcat, 192, 0, psum, psumsq, 64);
  bn_finalize_kernel<<<1, 64, 0, stream>>>(psum, psumsq, 64, gamma[1], beta[1], scale, shift, 1.f/16384.f, 64);
  apply_bn_kernel<<<NPT*64/256, 256, 0, stream>>>(xcat, 192, 0, 6, scale, shift);

  // ---- knn on x1 (fused dist+select; no materialized dist)
  xx_kernel<<<NPT/256, 256, 0, stream>>>(xcat, 192, 0, xx);
  knn_kernel<<<dim3(32,4,BB), 256, 0, stream>>>(xcat, 0, xx, candV, candI);
  knnmerge_kernel<<<NPT/256, 256, 0, stream>>>(candV, candI, idx);

  // ---- stage 2: edge-conv (W2): single gather pass (stats + vmax/vmin), then elementwise
  ut_kernel<<<NPT/4, 256, 0, stream>>>(xcat, 0, W2, U, T);
  gather_kernel<<<256, 256, 0, stream>>>(U, T, idx, psum, psumsq, vmaxB, vminB);
  bn_finalize_kernel<<<1, 64, 0, stream>>>(psum, psumsq, 256, gamma[2], beta[2], scale, shift, 1.f/327680.f, 64);
  gapply_kernel<<<NPT*64/256, 256, 0, stream>>>(vmaxB, vminB, scale, shift, xcat, 64);

  // ---- knn on x2
  xx_kernel<<<NPT/256, 256, 0, stream>>>(xcat, 192, 64, xx);
  knn_kernel<<<dim3(32,4,BB), 256, 0, stream>>>(xcat, 64, xx, candV, candI);
  knnmerge_kernel<<<NPT/256, 256, 0, stream>>>(candV, candI, idx);

  // ---- stage 3: edge-conv (W3) -> x3
  ut_kernel<<<NPT/4, 256, 0, stream>>>(xcat, 64, W3, U, T);
  gather_kernel<<<256, 256, 0, stream>>>(U, T, idx, psum, psumsq, vmaxB, vminB);
  bn_finalize_kernel<<<1, 64, 0, stream>>>(psum, psumsq, 256, gamma[3], beta[3], scale, shift, 1.f/327680.f, 64);
  gapply_kernel<<<NPT*64/256, 256, 0, stream>>>(vmaxB, vminB, scale, shift, xcat, 128);

  // ---- stage 4: conv4 as mm128 into r4 (dead scratch), then fused stats+minmax pass
  mm128_kernel<<<dim3(NPT/128, 4), 256, 0, stream>>>(xcat, 192, 128, W4, 64, r4, 512, nullptr, 512, 64, nullptr, nullptr);
  stats4_kernel<<<dim3(8,64), 256, 0, stream>>>(r4, psum, psumsq, pmax, pmin);
  bn_finalize_kernel<<<1, 512, 0, stream>>>(psum, psumsq, 64, gamma[4], beta[4], scale, shift, 1.f/16384.f, 512);
  x6v_kernel<<<8, 256, 0, stream>>>(pmax, pmin, scale, shift, x6v);
  bias5_kernel<<<8, 256, 0, stream>>>(W5, x6v, b5);

  // ---- stage 5: conv5 (704->512) = mm128 over packed 192 + bias5; r5 stays RAW
  mm128_kernel<<<dim3(NPT/128, 4), 256, 0, stream>>>(xcat, 192, 0, W5, 704, r5, 512, b5, 512, 192, nullptr, nullptr);
  stats_pm_kernel<<<dim3(8,64), 256, 0, stream>>>(r5, 512, 0, psum, psumsq, 512);
  bn_finalize_kernel<<<1, 512, 0, stream>>>(psum, psumsq, 64, gamma[5], beta[5], scale, shift, 1.f/16384.f, 512);

  // ---- stage 6: conv6 (512->256), BN5+lrelu on load; r6 stays RAW
  mm128_kernel<<<dim3(NPT/128, 2), 256, 0, stream>>>(r5, 512, 0, W6, 512, r6, 256, nullptr, 256, 512, scale, shift);
  stats_pm_kernel<<<dim3(4,64), 256, 0, stream>>>(r6, 256, 0, psum, psumsq, 256);
  bn_finalize_kernel<<<1, 256, 0, stream>>>(psum, psumsq, 64, gamma[6], beta[6], scale, shift, 1.f/16384.f, 256);

  // ---- stage 7: conv7 (256->128), BN6+lrelu on load; r7 stays RAW
  mm_kernel<<<dim3(NPT/128, 2), 256, 0, stream>>>(r6, 256, 0, W7, 256, r7, 128, nullptr, 128, 256, scale, shift);
  stats_pm_kernel<<<dim3(2,64), 256, 0, stream>>>(r7, 128, 0, psum, psumsq, 128);
  bn_finalize_kernel<<<1, 128, 0, stream>>>(psum, psumsq, 64, gamma[7], beta[7], scale, shift, 1.f/16384.f, 128);

  // ---- stage 8: conv8 (128->2) + bias, BN7+lrelu applied inline
  conv8_kernel<<<NPT/256, 256, 0, stream>>>(r7, W8, bias8, scale, shift, out);
}

// Round 12
// 1355.569 us; speedup vs baseline: 1.9916x; 1.9916x over previous
//
#include <hip/hip_runtime.h>
#include <math.h>

#define NN 4096
#define BB 4
#define NPT (NN*BB)
#define KK 20
#define EPSB 1e-5f

#define AS_STRIDE 132   // 128-point c-row, padded
#define WS_STRIDE 68    // 64-col c-row, padded
// Non-wrapping per-channel skew: staging writes 2-way (free), reads clean,
// all offsets multiples of 4 floats so float4 reads stay 16B-aligned.
#define SKEW(c) ((((((c)>>2)&7))<<2) + (((c)>>5)*28))

__device__ __forceinline__ float lrelu(float x){ return x >= 0.f ? x : 0.2f*x; }

// ---- stage 1: conv1 (3->64), writes raw into xcat[:, 0:64] (point-major, row stride 192)
__global__ void conv1_kernel(const float* __restrict__ x, const float* __restrict__ W1,
                             float* __restrict__ xcat){
  __shared__ float Wl[192];
  int tid = threadIdx.x;
  if (tid < 192) Wl[tid] = W1[tid];
  __syncthreads();
  int p = blockIdx.x*4 + (tid >> 6);
  int o = tid & 63;
  int b = p >> 12, n = p & 4095;
  const float* xb = x + (size_t)b*3*NN + n;
  float acc = Wl[o*3+0]*xb[0] + Wl[o*3+1]*xb[NN] + Wl[o*3+2]*xb[2*NN];
  xcat[(size_t)p*192 + o] = acc;
}

// ---- per-channel partial stats for point-major (NPT, C) buffer; deterministic slots
__global__ void stats_pm_kernel(const float* __restrict__ buf, int stride, int ofs,
                                float* __restrict__ psum, float* __restrict__ psumsq, int C){
  int tid = threadIdx.x;
  int lane = tid & 63, g = tid >> 6;
  int o = blockIdx.x*64 + lane;
  int p0 = blockIdx.y*256 + g*64;
  float s = 0.f, ss = 0.f;
  for (int i = 0; i < 64; ++i){
    float v = buf[(size_t)(p0+i)*stride + ofs + o];
    s += v; ss += v*v;
  }
  __shared__ float rs[4][64], rss[4][64];
  rs[g][lane] = s; rss[g][lane] = ss;
  __syncthreads();
  if (g == 0){
    s  = rs[0][lane]+rs[1][lane]+rs[2][lane]+rs[3][lane];
    ss = rss[0][lane]+rss[1][lane]+rss[2][lane]+rss[3][lane];
    psum[(size_t)blockIdx.y*C + o] = s;
    psumsq[(size_t)blockIdx.y*C + o] = ss;
  }
}

// deterministic finalize: serial sum over nparts partials per channel
__global__ void bn_finalize_kernel(const float* __restrict__ psum, const float* __restrict__ psumsq,
                                   int nparts,
                                   const float* __restrict__ gamma, const float* __restrict__ beta,
                                   float* __restrict__ scale, float* __restrict__ shift,
                                   float invcnt, int C){
  int o = threadIdx.x + blockIdx.x*blockDim.x;
  if (o >= C) return;
  float s = 0.f, ss = 0.f;
  for (int i = 0; i < nparts; ++i){
    s  += psum[(size_t)i*C + o];
    ss += psumsq[(size_t)i*C + o];
  }
  float m = s*invcnt;
  float v = ss*invcnt - m*m;
  v = fmaxf(v, 0.f);
  float sc = gamma[o] * rsqrtf(v + EPSB);
  scale[o] = sc;
  shift[o] = beta[o] - m*sc;
}

__global__ void apply_bn_kernel(float* __restrict__ buf, int stride, int ofs, int log2C,
                                const float* __restrict__ scale, const float* __restrict__ shift){
  int i = blockIdx.x*256 + threadIdx.x;
  int o = i & ((1<<log2C)-1);
  int p = i >> log2C;
  size_t a = (size_t)p*stride + ofs + o;
  float e = buf[a]*scale[o] + shift[o];
  buf[a] = lrelu(e);
}

// ---- ||x||^2 per point (64 features)
__global__ void xx_kernel(const float* __restrict__ xcat, int stride, int ofs,
                          float* __restrict__ xx){
  int p = blockIdx.x*256 + threadIdx.x;
  const float4* r = (const float4*)(xcat + (size_t)p*stride + ofs);
  float s = 0.f;
  #pragma unroll
  for (int i = 0; i < 16; ++i){ float4 v = r[i]; s += v.x*v.x + v.y*v.y + v.z*v.z + v.w*v.w; }
  xx[p] = s;
}

// ---- dist: 128n x 128m tile, split fragments, split staging. Bit-identical values
// to all previous dist variants (same ascending-c FMA chain per element).
__global__ void __launch_bounds__(256, 2)
dist_kernel(const float* __restrict__ xcat, int ofs,
            const float* __restrict__ xx, float* __restrict__ dist, int b){
  __shared__ float As[64*AS_STRIDE + 64];
  __shared__ float Bs[64*AS_STRIDE + 64];
  int tid = threadIdx.x;
  int n0 = blockIdx.x*128, m0 = blockIdx.y*128;
  const float* base = xcat + (size_t)b*NN*192 + ofs;
  int cgrp = (tid & 15)*4;
  float4 vin[8], vw[8];
  #pragma unroll
  for (int j = 0; j < 8; ++j){
    int row = (tid + 256*j) >> 4;
    vin[j] = *(const float4*)(base + (size_t)(n0+row)*192 + cgrp);
    vw[j]  = *(const float4*)(base + (size_t)(m0+row)*192 + cgrp);
  }
  #pragma unroll
  for (int j = 0; j < 8; ++j){
    int row = (tid + 256*j) >> 4, c4 = cgrp;
    float4 v = vin[j];
    As[(c4+0)*AS_STRIDE+SKEW(c4+0)+row]=v.x; As[(c4+1)*AS_STRIDE+SKEW(c4+1)+row]=v.y;
    As[(c4+2)*AS_STRIDE+SKEW(c4+2)+row]=v.z; As[(c4+3)*AS_STRIDE+SKEW(c4+3)+row]=v.w;
    float4 w = vw[j];
    Bs[(c4+0)*AS_STRIDE+SKEW(c4+0)+row]=w.x; Bs[(c4+1)*AS_STRIDE+SKEW(c4+1)+row]=w.y;
    Bs[(c4+2)*AS_STRIDE+SKEW(c4+2)+row]=w.z; Bs[(c4+3)*AS_STRIDE+SKEW(c4+3)+row]=w.w;
  }
  __syncthreads();
  int pA = (tid >> 4)*4, oB = (tid & 15)*4;
  float acc[8][8] = {};   // i: 0-3 rows pA+i, 4-7 rows pA+64+(i-4); j likewise cols
  for (int c = 0; c < 64; ++c){
    const float* arow = &As[c*AS_STRIDE + SKEW(c)];
    const float* brow = &Bs[c*AS_STRIDE + SKEW(c)];
    float4 a0 = *(const float4*)&arow[pA];
    float4 a1 = *(const float4*)&arow[pA + 64];
    float4 b0 = *(const float4*)&brow[oB];
    float4 b1 = *(const float4*)&brow[oB + 64];
    float av[8] = {a0.x,a0.y,a0.z,a0.w,a1.x,a1.y,a1.z,a1.w};
    float bv[8] = {b0.x,b0.y,b0.z,b0.w,b1.x,b1.y,b1.z,b1.w};
    #pragma unroll
    for (int i = 0; i < 8; ++i)
      #pragma unroll
      for (int j = 0; j < 8; ++j)
        acc[i][j] += av[i]*bv[j];
  }
  float xm[8];
  #pragma unroll
  for (int j = 0; j < 4; ++j){
    xm[j]   = xx[b*NN + m0 + oB + j];
    xm[4+j] = xx[b*NN + m0 + 64 + oB + j];
  }
  #pragma unroll
  for (int h = 0; h < 2; ++h){
    #pragma unroll
    for (int i = 0; i < 4; ++i){
      int row = n0 + h*64 + pA + i;
      float xn = xx[b*NN + row];
      int ai = h*4 + i;
      float4 w0, w1;
      w0.x = 2.f*acc[ai][0] - xn - xm[0]; w0.y = 2.f*acc[ai][1] - xn - xm[1];
      w0.z = 2.f*acc[ai][2] - xn - xm[2]; w0.w = 2.f*acc[ai][3] - xn - xm[3];
      w1.x = 2.f*acc[ai][4] - xn - xm[4]; w1.y = 2.f*acc[ai][5] - xn - xm[5];
      w1.z = 2.f*acc[ai][6] - xn - xm[6]; w1.w = 2.f*acc[ai][7] - xn - xm[7];
      float* drow = dist + (size_t)row*NN + m0;
      *(float4*)(drow + oB) = w0;
      *(float4*)(drow + 64 + oB) = w1;
    }
  }
}

// ---- per-row top-20 via radix select (set semantics; boundary tie -> smallest index).
__global__ void topk_kernel(const float* __restrict__ dist, int* __restrict__ idxout){
  int n = blockIdx.x;
  int tid = threadIdx.x;
  int wv = tid >> 6;
  const float* row = dist + (size_t)n*NN;
  unsigned k[16];
  #pragma unroll
  for (int i = 0; i < 16; ++i){
    unsigned u = __float_as_uint(row[tid + (i<<8)]);
    k[i] = u ^ (unsigned)(((int)u >> 31) | 0x80000000);  // monotone float->uint
  }
  __shared__ unsigned hist[4][256];
  __shared__ unsigned sufx[257];
  __shared__ unsigned selw[1];
  __shared__ unsigned toff[256];
  __shared__ int mred[4];
  unsigned remaining = KK;
  unsigned prefix = 0;
  #pragma unroll
  for (int lvl = 0; lvl < 4; ++lvl){
    int shift = 24 - lvl*8;
    hist[0][tid]=0; hist[1][tid]=0; hist[2][tid]=0; hist[3][tid]=0;
    __syncthreads();
    unsigned pmask = (lvl == 0) ? 0u : (0xFFFFFFFFu << (shift + 8));
    #pragma unroll
    for (int i = 0; i < 16; ++i){
      if ((k[i] & pmask) == prefix)
        atomicAdd(&hist[wv][(k[i] >> shift) & 255], 1u);
    }
    __syncthreads();
    if (tid < 64){
      unsigned h[4];
      #pragma unroll
      for (int q = 0; q < 4; ++q)
        h[q] = hist[0][tid*4+q]+hist[1][tid*4+q]+hist[2][tid*4+q]+hist[3][tid*4+q];
      unsigned lane_sum = h[0]+h[1]+h[2]+h[3];
      unsigned acc = lane_sum;
      #pragma unroll
      for (int s = 1; s < 64; s <<= 1){
        unsigned o = __shfl_down(acc, s);
        if (tid + s < 64) acc += o;
      }
      unsigned excl = acc - lane_sum;          // sum over lanes > me
      sufx[tid*4+3] = excl + h[3];
      sufx[tid*4+2] = excl + h[3] + h[2];
      sufx[tid*4+1] = excl + h[3] + h[2] + h[1];
      sufx[tid*4+0] = excl + h[3] + h[2] + h[1] + h[0];
      if (tid == 0) sufx[256] = 0;
    }
    __syncthreads();
    unsigned s_d = sufx[tid], s_d1 = sufx[tid+1];
    if (s_d >= remaining && s_d1 < remaining) selw[0] = tid;   // exactly one thread
    __syncthreads();
    unsigned d = selw[0];
    remaining -= sufx[d+1];
    prefix |= d << shift;
  }
  unsigned K20 = prefix;        // exact 20th-largest key
  unsigned r = remaining;       // slots for keys == K20 (take smallest indices)
  unsigned mycount = 0;
  #pragma unroll
  for (int i = 0; i < 16; ++i) if (k[i] > K20) mycount++;
  toff[tid] = mycount;
  __syncthreads();
  if (tid < 64){
    unsigned c0=toff[tid*4], c1=toff[tid*4+1], c2=toff[tid*4+2], c3=toff[tid*4+3];
    unsigned lane_sum = c0+c1+c2+c3;
    unsigned acc = lane_sum;
    #pragma unroll
    for (int s = 1; s < 64; s <<= 1){
      unsigned o = __shfl_up(acc, s);
      if ((int)tid - s >= 0) acc += o;
    }
    unsigned excl = acc - lane_sum;            // sum over lanes < me
    sufx[tid*4+0] = excl;
    sufx[tid*4+1] = excl + c0;
    sufx[tid*4+2] = excl + c0 + c1;
    sufx[tid*4+3] = excl + c0 + c1 + c2;
  }
  __syncthreads();
  unsigned pos = sufx[tid];
  int* orow = idxout + n*KK;
  #pragma unroll
  for (int i = 0; i < 16; ++i)
    if (k[i] > K20) orow[pos++] = tid + (i<<8);
  unsigned A = KK - r;
  int last = -1;
  for (unsigned t = 0; t < r; ++t){
    int best = 0x7fffffff;
    #pragma unroll
    for (int i = 0; i < 16; ++i){
      int m = tid + (i<<8);
      if (k[i] == K20 && m > last && m < best) best = m;
    }
    #pragma unroll
    for (int s = 32; s > 0; s >>= 1){
      int o = __shfl_down(best, s);
      best = min(best, o);
    }
    if ((tid & 63) == 0) mred[tid >> 6] = best;
    __syncthreads();
    int w = min(min(mred[0],mred[1]), min(mred[2],mred[3]));
    if (tid == 0) orow[A + t] = w;
    last = w;
    __syncthreads();
  }
}

// ---- U = W[:, :64] * x ; T = (W[:,64:] - W[:, :64]) * x  (per point, point-major out)
__global__ void ut_kernel(const float* __restrict__ xcat, int ofs, const float* __restrict__ W,
                          float* __restrict__ U, float* __restrict__ T){
  __shared__ float Wl[64*129];
  int tid = threadIdx.x;
  for (int i = tid; i < 64*128; i += 256){
    int o = i >> 7, c = i & 127;
    Wl[o*129 + c] = W[i];
  }
  __syncthreads();
  int g = tid >> 6, lane = tid & 63;
  int p = blockIdx.x*4 + g;
  float xv = xcat[(size_t)p*192 + ofs + lane];
  const float* wr = Wl + lane*129;
  float u = 0.f, t = 0.f;
  for (int c = 0; c < 64; ++c){
    float xc = __shfl(xv, c);
    float wa = wr[c], wb = wr[64+c];
    u += wa*xc;
    t += (wb - wa)*xc;
  }
  U[(size_t)p*64 + lane] = u;
  T[(size_t)p*64 + lane] = t;
}

// ---- ONE gather pass: v = U[j]+T[n] over k -> per-channel partial sum/sumsq
// (deterministic slots) AND per-(point,ch) vmax/vmin (lrelu-monotone max trick).
__global__ void gather_kernel(const float* __restrict__ U, const float* __restrict__ T,
                              const int* __restrict__ idx,
                              float* __restrict__ psum, float* __restrict__ psumsq,
                              float* __restrict__ vmax, float* __restrict__ vmin){
  int tid = threadIdx.x;
  int g = tid >> 6, lane = tid & 63;
  int p0 = blockIdx.x*64 + g*16;
  float s = 0.f, ss = 0.f;
  for (int pi = 0; pi < 16; ++pi){
    int p = p0 + pi;
    int base = (p >> 12) << 12;
    float t = T[(size_t)p*64 + lane];
    const int* ir = idx + (size_t)p*KK;
    float mx = -INFINITY, mn = INFINITY;
    for (int k = 0; k < KK; ++k){
      int j = ir[k];
      float v = U[(size_t)(base + j)*64 + lane] + t;
      s += v; ss += v*v;
      mx = fmaxf(mx, v); mn = fminf(mn, v);
    }
    vmax[(size_t)p*64 + lane] = mx;
    vmin[(size_t)p*64 + lane] = mn;
  }
  __shared__ float rs[4][64], rss[4][64];
  rs[g][lane] = s; rss[g][lane] = ss;
  __syncthreads();
  if (g == 0){
    s  = rs[0][lane]+rs[1][lane]+rs[2][lane]+rs[3][lane];
    ss = rss[0][lane]+rss[1][lane]+rss[2][lane]+rss[3][lane];
    psum[(size_t)blockIdx.x*64 + lane] = s;
    psumsq[(size_t)blockIdx.x*64 + lane] = ss;
  }
}

// ---- elementwise: x_out[p,o] = lrelu(s*(s>=0?vmax:vmin)+t) -> xcat[:, ofs:ofs+64]
__global__ void gapply_kernel(const float* __restrict__ vmax, const float* __restrict__ vmin,
                              const float* __restrict__ scale, const float* __restrict__ shift,
                              float* __restrict__ xcat, int ofs){
  int i = blockIdx.x*256 + threadIdx.x;
  int p = i >> 6, o = i & 63;
  float s = scale[o];
  float v = (s >= 0.f) ? vmax[i] : vmin[i];
  xcat[(size_t)p*192 + ofs + o] = lrelu(s*v + shift[o]);
}

// ---- point-major matmul, 128p x 64o tile, 8x4 acc/thread (conv7), split staging.
__global__ void __launch_bounds__(256, 2)
mm_kernel(const float* __restrict__ in, int inStride, int inOfs,
          const float* __restrict__ W, int wStride,
          float* __restrict__ out, int outStride,
          const float* __restrict__ bias, int O, int I,
          const float* __restrict__ bnScale, const float* __restrict__ bnShift){
  __shared__ float As[64*AS_STRIDE + 64];
  __shared__ float Ws[64*WS_STRIDE + 64];
  int tid = threadIdx.x;
  int p0 = blockIdx.x*128, o0 = blockIdx.y*64;
  int psub = (tid >> 4)*8, osub = (tid & 15)*4;
  int cgrp = (tid & 15)*4;
  float acc[8][4] = {};
  for (int cc = 0; cc < I; cc += 64){
    float4 sc4 = make_float4(1.f,1.f,1.f,1.f), sh4 = make_float4(0.f,0.f,0.f,0.f);
    if (bnScale){
      sc4 = *(const float4*)(bnScale + cc + cgrp);
      sh4 = *(const float4*)(bnShift + cc + cgrp);
    }
    float4 vin[8], vw[4];
    #pragma unroll
    for (int j = 0; j < 8; ++j){
      int row = (tid + 256*j) >> 4;
      vin[j] = *(const float4*)(in + (size_t)(p0+row)*inStride + inOfs + cc + cgrp);
    }
    #pragma unroll
    for (int j = 0; j < 4; ++j){
      int row = (tid + 256*j) >> 4;
      vw[j] = *(const float4*)(W + (size_t)(o0+row)*wStride + cc + cgrp);
    }
    #pragma unroll
    for (int j = 0; j < 8; ++j){
      int row = (tid + 256*j) >> 4, c4 = cgrp;
      float4 v = vin[j];
      if (bnScale){
        v.x = lrelu(v.x*sc4.x + sh4.x); v.y = lrelu(v.y*sc4.y + sh4.y);
        v.z = lrelu(v.z*sc4.z + sh4.z); v.w = lrelu(v.w*sc4.w + sh4.w);
      }
      As[(c4+0)*AS_STRIDE+SKEW(c4+0)+row]=v.x; As[(c4+1)*AS_STRIDE+SKEW(c4+1)+row]=v.y;
      As[(c4+2)*AS_STRIDE+SKEW(c4+2)+row]=v.z; As[(c4+3)*AS_STRIDE+SKEW(c4+3)+row]=v.w;
    }
    #pragma unroll
    for (int j = 0; j < 4; ++j){
      int row = (tid + 256*j) >> 4, c4 = cgrp;
      float4 v = vw[j];
      Ws[(c4+0)*WS_STRIDE+SKEW(c4+0)+row]=v.x; Ws[(c4+1)*WS_STRIDE+SKEW(c4+1)+row]=v.y;
      Ws[(c4+2)*WS_STRIDE+SKEW(c4+2)+row]=v.z; Ws[(c4+3)*WS_STRIDE+SKEW(c4+3)+row]=v.w;
    }
    __syncthreads();
    for (int c = 0; c < 64; ++c){
      const float* arow = &As[c*AS_STRIDE + SKEW(c)];
      const float* brow = &Ws[c*WS_STRIDE + SKEW(c)];
      float4 a0 = *(const float4*)&arow[psub];
      float4 a1 = *(const float4*)&arow[psub + 4];
      float4 bb = *(const float4*)&brow[osub];
      float av[8] = {a0.x,a0.y,a0.z,a0.w,a1.x,a1.y,a1.z,a1.w};
      float bv[4] = {bb.x,bb.y,bb.z,bb.w};
      #pragma unroll
      for (int i = 0; i < 8; ++i)
        #pragma unroll
        for (int j = 0; j < 4; ++j)
          acc[i][j] += av[i]*bv[j];
    }
    __syncthreads();
  }
  int bIdx = p0 >> 12;
  float bb0=0.f, bb1=0.f, bb2=0.f, bb3=0.f;
  if (bias){
    bb0 = bias[bIdx*O + o0 + osub + 0];
    bb1 = bias[bIdx*O + o0 + osub + 1];
    bb2 = bias[bIdx*O + o0 + osub + 2];
    bb3 = bias[bIdx*O + o0 + osub + 3];
  }
  #pragma unroll
  for (int i = 0; i < 8; ++i){
    float4 w;
    w.x = acc[i][0]+bb0; w.y = acc[i][1]+bb1; w.z = acc[i][2]+bb2; w.w = acc[i][3]+bb3;
    *(float4*)(out + (size_t)(p0+psub+i)*outStride + o0 + osub) = w;
  }
}

// ---- point-major matmul, 128p x 128o tile, 8x8 acc/thread, split fragments,
// split staging (conv5/conv6).
__global__ void __launch_bounds__(256, 2)
mm128_kernel(const float* __restrict__ in, int inStride, int inOfs,
             const float* __restrict__ W, int wStride,
             float* __restrict__ out, int outStride,
             const float* __restrict__ bias, int O, int I,
             const float* __restrict__ bnScale, const float* __restrict__ bnShift){
  __shared__ float As[64*AS_STRIDE + 64];
  __shared__ float Ws[64*AS_STRIDE + 64];
  int tid = threadIdx.x;
  int p0 = blockIdx.x*128, o0 = blockIdx.y*128;
  int pA = (tid >> 4)*4, oB = (tid & 15)*4;
  int cgrp = (tid & 15)*4;
  float acc[8][8] = {};
  for (int cc = 0; cc < I; cc += 64){
    float4 sc4 = make_float4(1.f,1.f,1.f,1.f), sh4 = make_float4(0.f,0.f,0.f,0.f);
    if (bnScale){
      sc4 = *(const float4*)(bnScale + cc + cgrp);
      sh4 = *(const float4*)(bnShift + cc + cgrp);
    }
    float4 vin[8], vw[8];
    #pragma unroll
    for (int j = 0; j < 8; ++j){
      int row = (tid + 256*j) >> 4;
      vin[j] = *(const float4*)(in + (size_t)(p0+row)*inStride + inOfs + cc + cgrp);
      vw[j]  = *(const float4*)(W + (size_t)(o0+row)*wStride + cc + cgrp);
    }
    #pragma unroll
    for (int j = 0; j < 8; ++j){
      int row = (tid + 256*j) >> 4, c4 = cgrp;
      float4 v = vin[j];
      if (bnScale){
        v.x = lrelu(v.x*sc4.x + sh4.x); v.y = lrelu(v.y*sc4.y + sh4.y);
        v.z = lrelu(v.z*sc4.z + sh4.z); v.w = lrelu(v.w*sc4.w + sh4.w);
      }
      As[(c4+0)*AS_STRIDE+SKEW(c4+0)+row]=v.x; As[(c4+1)*AS_STRIDE+SKEW(c4+1)+row]=v.y;
      As[(c4+2)*AS_STRIDE+SKEW(c4+2)+row]=v.z; As[(c4+3)*AS_STRIDE+SKEW(c4+3)+row]=v.w;
      float4 w = vw[j];
      Ws[(c4+0)*AS_STRIDE+SKEW(c4+0)+row]=w.x; Ws[(c4+1)*AS_STRIDE+SKEW(c4+1)+row]=w.y;
      Ws[(c4+2)*AS_STRIDE+SKEW(c4+2)+row]=w.z; Ws[(c4+3)*AS_STRIDE+SKEW(c4+3)+row]=w.w;
    }
    __syncthreads();
    for (int c = 0; c < 64; ++c){
      const float* arow = &As[c*AS_STRIDE + SKEW(c)];
      const float* brow = &Ws[c*AS_STRIDE + SKEW(c)];
      float4 a0 = *(const float4*)&arow[pA];
      float4 a1 = *(const float4*)&arow[pA + 64];
      float4 b0 = *(const float4*)&brow[oB];
      float4 b1 = *(const float4*)&brow[oB + 64];
      float av[8] = {a0.x,a0.y,a0.z,a0.w,a1.x,a1.y,a1.z,a1.w};
      float bv[8] = {b0.x,b0.y,b0.z,b0.w,b1.x,b1.y,b1.z,b1.w};
      #pragma unroll
      for (int i = 0; i < 8; ++i)
        #pragma unroll
        for (int j = 0; j < 8; ++j)
          acc[i][j] += av[i]*bv[j];
    }
    __syncthreads();
  }
  int bIdx = p0 >> 12;
  float bb[8] = {0.f,0.f,0.f,0.f,0.f,0.f,0.f,0.f};
  if (bias){
    #pragma unroll
    for (int j = 0; j < 4; ++j){
      bb[j]   = bias[bIdx*O + o0 + oB + j];
      bb[4+j] = bias[bIdx*O + o0 + 64 + oB + j];
    }
  }
  #pragma unroll
  for (int h = 0; h < 2; ++h){
    #pragma unroll
    for (int i = 0; i < 4; ++i){
      int row = p0 + h*64 + pA + i;
      int ai = h*4 + i;
      float4 w0, w1;
      w0.x = acc[ai][0]+bb[0]; w0.y = acc[ai][1]+bb[1];
      w0.z = acc[ai][2]+bb[2]; w0.w = acc[ai][3]+bb[3];
      w1.x = acc[ai][4]+bb[4]; w1.y = acc[ai][5]+bb[5];
      w1.z = acc[ai][6]+bb[6]; w1.w = acc[ai][7]+bb[7];
      float* orow = out + (size_t)row*outStride + o0;
      *(float4*)(orow + oB) = w0;
      *(float4*)(orow + 64 + oB) = w1;
    }
  }
}

// ---- conv4 FUSED with stats: computes the 128x128 r4 tile in registers, then
// reduces in-block to per-channel sum/sumsq partials + per-(tile,ch) max/min.
// r4 is NEVER materialized (saves its 33.5 MB write + 33.5 MB stats re-read).
// grid (NPT/128, 512/128): part index = blockIdx.x (128 parts), ch = o0+col.
__global__ void __launch_bounds__(256, 2)
conv4stats_kernel(const float* __restrict__ xcat, const float* __restrict__ W4,
                  float* __restrict__ psum, float* __restrict__ psumsq,
                  float* __restrict__ pmax, float* __restrict__ pmin){
  __shared__ float As[64*AS_STRIDE + 64];
  __shared__ float Ws[64*AS_STRIDE + 64];
  int tid = threadIdx.x;
  int p0 = blockIdx.x*128, o0 = blockIdx.y*128;
  int pA = (tid >> 4)*4, oB = (tid & 15)*4;
  int cgrp = (tid & 15)*4;
  float4 vin[8], vw[8];
  #pragma unroll
  for (int j = 0; j < 8; ++j){
    int row = (tid + 256*j) >> 4;
    vin[j] = *(const float4*)(xcat + (size_t)(p0+row)*192 + 128 + cgrp);
    vw[j]  = *(const float4*)(W4 + (size_t)(o0+row)*64 + cgrp);
  }
  #pragma unroll
  for (int j = 0; j < 8; ++j){
    int row = (tid + 256*j) >> 4, c4 = cgrp;
    float4 v = vin[j];
    As[(c4+0)*AS_STRIDE+SKEW(c4+0)+row]=v.x; As[(c4+1)*AS_STRIDE+SKEW(c4+1)+row]=v.y;
    As[(c4+2)*AS_STRIDE+SKEW(c4+2)+row]=v.z; As[(c4+3)*AS_STRIDE+SKEW(c4+3)+row]=v.w;
    float4 w = vw[j];
    Ws[(c4+0)*AS_STRIDE+SKEW(c4+0)+row]=w.x; Ws[(c4+1)*AS_STRIDE+SKEW(c4+1)+row]=w.y;
    Ws[(c4+2)*AS_STRIDE+SKEW(c4+2)+row]=w.z; Ws[(c4+3)*AS_STRIDE+SKEW(c4+3)+row]=w.w;
  }
  __syncthreads();
  float acc[8][8] = {};
  for (int c = 0; c < 64; ++c){
    const float* arow = &As[c*AS_STRIDE + SKEW(c)];
    const float* brow = &Ws[c*AS_STRIDE + SKEW(c)];
    float4 a0 = *(const float4*)&arow[pA];
    float4 a1 = *(const float4*)&arow[pA + 64];
    float4 b0 = *(const float4*)&brow[oB];
    float4 b1 = *(const float4*)&brow[oB + 64];
    float av[8] = {a0.x,a0.y,a0.z,a0.w,a1.x,a1.y,a1.z,a1.w};
    float bv[8] = {b0.x,b0.y,b0.z,b0.w,b1.x,b1.y,b1.z,b1.w};
    #pragma unroll
    for (int i = 0; i < 8; ++i)
      #pragma unroll
      for (int j = 0; j < 8; ++j)
        acc[i][j] += av[i]*bv[j];
  }
  // per-thread column partials over its 8 rows (fixed order i=0..7)
  float cs[8], cq[8], cmx[8], cmn[8];
  #pragma unroll
  for (int j = 0; j < 8; ++j){
    float s = 0.f, q = 0.f, mx = -INFINITY, mn = INFINITY;
    #pragma unroll
    for (int i = 0; i < 8; ++i){
      float v = acc[i][j];
      s += v; q += v*v; mx = fmaxf(mx, v); mn = fminf(mn, v);
    }
    cs[j]=s; cq[j]=q; cmx[j]=mx; cmn[j]=mn;
  }
  __syncthreads();   // done reading As/Ws; reuse as scratch
  int r = tid >> 4;
  #pragma unroll
  for (int j = 0; j < 8; ++j){
    int col = (j < 4) ? (oB + j) : (64 + oB + (j-4));
    As[r*128 + col]        = cs[j];
    As[2048 + r*128 + col] = cq[j];
    Ws[r*128 + col]        = cmx[j];
    Ws[2048 + r*128 + col] = cmn[j];
  }
  __syncthreads();
  if (tid < 128){
    float ts = 0.f, tq = 0.f, tm = -INFINITY, tn = INFINITY;
    for (int rr = 0; rr < 16; ++rr){
      ts += As[rr*128 + tid];
      tq += As[2048 + rr*128 + tid];
      tm = fmaxf(tm, Ws[rr*128 + tid]);
      tn = fminf(tn, Ws[2048 + rr*128 + tid]);
    }
    size_t slot = (size_t)blockIdx.x*512 + o0 + tid;
    psum[slot] = ts; psumsq[slot] = tq; pmax[slot] = tm; pmin[slot] = tn;
  }
}

// lrelu(s*v+t) monotone in v: use max if s>=0 else min  (32 tiles per batch)
__global__ void x6v_kernel(const float* __restrict__ pmax, const float* __restrict__ pmin,
                           const float* __restrict__ scale, const float* __restrict__ shift,
                           float* __restrict__ x6v){
  int t = blockIdx.x*256 + threadIdx.x;
  int b = t >> 9, o = t & 511;
  float mx = -INFINITY, mn = INFINITY;
  for (int pt = b*32; pt < b*32+32; ++pt){
    mx = fmaxf(mx, pmax[(size_t)pt*512 + o]);
    mn = fminf(mn, pmin[(size_t)pt*512 + o]);
  }
  float s = scale[o];
  float v = (s >= 0.f) ? mx : mn;
  x6v[t] = lrelu(s*v + shift[o]);
}

// bias5[b,o] = sum_c W5[o, 192+c] * x6v[b,c]   (the broadcast part of the concat)
__global__ void bias5_kernel(const float* __restrict__ W5, const float* __restrict__ x6v,
                             float* __restrict__ b5){
  __shared__ float xl[512];
  int tid = threadIdx.x;
  int t = blockIdx.x*256 + tid;
  int b = t >> 9, o = t & 511;
  for (int i = tid; i < 512; i += 256) xl[i] = x6v[(b<<9) + i];
  __syncthreads();
  const float* wr = W5 + (size_t)o*704 + 192;
  float acc = 0.f;
  for (int c = 0; c < 512; ++c) acc += wr[c]*xl[c];
  b5[t] = acc;
}

// ---- conv8 (128->2) + bias over raw r7 with BN7+lrelu applied inline
__global__ void conv8_kernel(const float* __restrict__ r7, const float* __restrict__ W8,
                             const float* __restrict__ bias8,
                             const float* __restrict__ scale, const float* __restrict__ shift,
                             float* __restrict__ out){
  __shared__ float Wl[256];
  __shared__ float scl[128], shl[128];
  int tid = threadIdx.x;
  Wl[tid] = W8[tid];
  if (tid < 128){ scl[tid] = scale[tid]; shl[tid] = shift[tid]; }
  __syncthreads();
  int p = blockIdx.x*256 + tid;
  int b = p >> 12, n = p & 4095;
  const float4* row = (const float4*)(r7 + (size_t)p*128);
  float a0 = 0.f, a1 = 0.f;
  #pragma unroll
  for (int i = 0; i < 32; ++i){
    float4 v = row[i];
    v.x = lrelu(v.x*scl[i*4+0] + shl[i*4+0]);
    v.y = lrelu(v.y*scl[i*4+1] + shl[i*4+1]);
    v.z = lrelu(v.z*scl[i*4+2] + shl[i*4+2]);
    v.w = lrelu(v.w*scl[i*4+3] + shl[i*4+3]);
    a0 += v.x*Wl[i*4] + v.y*Wl[i*4+1] + v.z*Wl[i*4+2] + v.w*Wl[i*4+3];
    a1 += v.x*Wl[128+i*4] + v.y*Wl[128+i*4+1] + v.z*Wl[128+i*4+2] + v.w*Wl[128+i*4+3];
  }
  out[(size_t)(b*2+0)*NN + n] = a0 + bias8[0];
  out[(size_t)(b*2+1)*NN + n] = a1 + bias8[1];
}

extern "C" void kernel_launch(void* const* d_in, const int* in_sizes, int n_in,
                              void* d_out, int out_size, void* d_ws, size_t ws_size,
                              hipStream_t stream){
  const float* x     = (const float*)d_in[0];
  const float* W1    = (const float*)d_in[1];
  const float* W2    = (const float*)d_in[2];
  const float* W3    = (const float*)d_in[3];
  const float* W4    = (const float*)d_in[4];
  const float* W5    = (const float*)d_in[5];
  const float* W6    = (const float*)d_in[6];
  const float* W7    = (const float*)d_in[7];
  const float* W8    = (const float*)d_in[8];
  const float* bias8 = (const float*)d_in[9];
  const float* gamma[8]; const float* beta[8];
  for (int i = 1; i <= 7; ++i){
    gamma[i] = (const float*)d_in[10 + 2*(i-1)];
    beta[i]  = (const float*)d_in[11 + 2*(i-1)];
  }
  float* out = (float*)d_out;

  float* ws = (float*)d_ws;
  size_t off = 0;
  float* xcat  = ws + off; off += (size_t)NPT*192;   // x1|x2|x3 packed, stride 192
  float* U     = ws + off; off += (size_t)NPT*64;
  float* T     = ws + off; off += (size_t)NPT*64;
  float* xx    = ws + off; off += NPT;
  int*   idx   = (int*)(ws + off); off += (size_t)NPT*KK;
  float* psum  = ws + off; off += 128*512;
  float* psumsq= ws + off; off += 128*512;
  float* pmax  = ws + off; off += 128*512;
  float* pmin  = ws + off; off += 128*512;
  float* scale = ws + off; off += 512;
  float* shift = ws + off; off += 512;
  float* x6v   = ws + off; off += 2048;
  float* b5    = ws + off; off += 2048;
  float* big   = ws + off;   // time-shared: dist (knn) / vmax|vmin (gather) / r5|r6|r7
  float* dist  = big;                               // 16.8M floats (one batch)
  float* vmaxB = big;                               // NPT*64, live only between knn rounds
  float* vminB = big + (size_t)NPT*64;
  float* r5    = big;
  float* r6    = big + (size_t)NPT*512;
  float* r7    = big + (size_t)NPT*512 + (size_t)NPT*256;

  // ---- stage 1: conv1 + BN(train stats) + lrelu -> x1 (xcat[:,0:64])
  conv1_kernel<<<NPT/4, 256, 0, stream>>>(x, W1, xcat);
  stats_pm_kernel<<<dim3(1,64), 256, 0, stream>>>(xcat, 192, 0, psum, psumsq, 64);
  bn_finalize_kernel<<<1, 64, 0, stream>>>(psum, psumsq, 64, gamma[1], beta[1], scale, shift, 1.f/16384.f, 64);
  apply_bn_kernel<<<NPT*64/256, 256, 0, stream>>>(xcat, 192, 0, 6, scale, shift);

  // ---- knn on x1 (materialized per-batch dist: L3-resident round trip)
  xx_kernel<<<NPT/256, 256, 0, stream>>>(xcat, 192, 0, xx);
  for (int b = 0; b < BB; ++b){
    dist_kernel<<<dim3(32,32), 256, 0, stream>>>(xcat, 0, xx, dist, b);
    topk_kernel<<<NN, 256, 0, stream>>>(dist, idx + (size_t)b*NN*KK);
  }

  // ---- stage 2: edge-conv (W2): single gather pass (stats + vmax/vmin), then elementwise
  ut_kernel<<<NPT/4, 256, 0, stream>>>(xcat, 0, W2, U, T);
  gather_kernel<<<256, 256, 0, stream>>>(U, T, idx, psum, psumsq, vmaxB, vminB);
  bn_finalize_kernel<<<1, 64, 0, stream>>>(psum, psumsq, 256, gamma[2], beta[2], scale, shift, 1.f/327680.f, 64);
  gapply_kernel<<<NPT*64/256, 256, 0, stream>>>(vmaxB, vminB, scale, shift, xcat, 64);

  // ---- knn on x2
  xx_kernel<<<NPT/256, 256, 0, stream>>>(xcat, 192, 64, xx);
  for (int b = 0; b < BB; ++b){
    dist_kernel<<<dim3(32,32), 256, 0, stream>>>(xcat, 64, xx, dist, b);
    topk_kernel<<<NN, 256, 0, stream>>>(dist, idx + (size_t)b*NN*KK);
  }

  // ---- stage 3: edge-conv (W3) -> x3
  ut_kernel<<<NPT/4, 256, 0, stream>>>(xcat, 64, W3, U, T);
  gather_kernel<<<256, 256, 0, stream>>>(U, T, idx, psum, psumsq, vmaxB, vminB);
  bn_finalize_kernel<<<1, 64, 0, stream>>>(psum, psumsq, 256, gamma[3], beta[3], scale, shift, 1.f/327680.f, 64);
  gapply_kernel<<<NPT*64/256, 256, 0, stream>>>(vmaxB, vminB, scale, shift, xcat, 128);

  // ---- stage 4: conv4 fused with stats (r4 never materialized)
  conv4stats_kernel<<<dim3(NPT/128, 4), 256, 0, stream>>>(xcat, W4, psum, psumsq, pmax, pmin);
  bn_finalize_kernel<<<1, 512, 0, stream>>>(psum, psumsq, 128, gamma[4], beta[4], scale, shift, 1.f/16384.f, 512);
  x6v_kernel<<<8, 256, 0, stream>>>(pmax, pmin, scale, shift, x6v);
  bias5_kernel<<<8, 256, 0, stream>>>(W5, x6v, b5);

  // ---- stage 5: conv5 (704->512) = mm128 over packed 192 + bias5; r5 stays RAW
  mm128_kernel<<<dim3(NPT/128, 4), 256, 0, stream>>>(xcat, 192, 0, W5, 704, r5, 512, b5, 512, 192, nullptr, nullptr);
  stats_pm_kernel<<<dim3(8,64), 256, 0, stream>>>(r5, 512, 0, psum, psumsq, 512);
  bn_finalize_kernel<<<1, 512, 0, stream>>>(psum, psumsq, 64, gamma[5], beta[5], scale, shift, 1.f/16384.f, 512);

  // ---- stage 6: conv6 (512->256), BN5+lrelu on load; r6 stays RAW
  mm128_kernel<<<dim3(NPT/128, 2), 256, 0, stream>>>(r5, 512, 0, W6, 512, r6, 256, nullptr, 256, 512, scale, shift);
  stats_pm_kernel<<<dim3(4,64), 256, 0, stream>>>(r6, 256, 0, psum, psumsq, 256);
  bn_finalize_kernel<<<1, 256, 0, stream>>>(psum, psumsq, 64, gamma[6], beta[6], scale, shift, 1.f/16384.f, 256);

  // ---- stage 7: conv7 (256->128), BN6+lrelu on load; r7 stays RAW
  mm_kernel<<<dim3(NPT/128, 2), 256, 0, stream>>>(r6, 256, 0, W7, 256, r7, 128, nullptr, 128, 256, scale, shift);
  stats_pm_kernel<<<dim3(2,64), 256, 0, stream>>>(r7, 128, 0, psum, psumsq, 128);
  bn_finalize_kernel<<<1, 128, 0, stream>>>(psum, psumsq, 64, gamma[7], beta[7], scale, shift, 1.f/16384.f, 128);

  // ---- stage 8: conv8 (128->2) + bias, BN7+lrelu applied inline
  conv8_kernel<<<NPT/256, 256, 0, stream>>>(r7, W8, bias8, scale, shift, out);
}